// Round 9
// baseline (95.406 us; speedup 1.0000x reference)
//
#include <hip/hip_runtime.h>
#include <cfloat>

#define KC   32768
#define NPTS 8192
#define TPB  256
#define PPT  4
#define PTS_PER_BLK (TPB * PPT)        // 1024
#define NPB  (NPTS / PTS_PER_BLK)      // 8

typedef float v2f __attribute__((ext_vector_type(2)));

// Packed fp32 (IEEE per 32-bit half) — bit-identical to scalar chain (verified R1-R4)
__device__ __forceinline__ v2f pk_mul(v2f a, v2f b) {
    v2f d; asm("v_pk_mul_f32 %0, %1, %2" : "=v"(d) : "v"(a), "v"(b)); return d;
}
__device__ __forceinline__ v2f pk_fma(v2f a, v2f b, v2f c) {
    v2f d; asm("v_pk_fma_f32 %0, %1, %2, %3" : "=v"(d) : "v"(a), "v"(b), "v"(c)); return d;
}
__device__ __forceinline__ v2f pk_add(v2f a, v2f b) {
    v2f d; asm("v_pk_add_f32 %0, %1, %2" : "=v"(d) : "v"(a), "v"(b)); return d;
}
__device__ __forceinline__ float min3f(float a, float b, float c) {
    float d; asm("v_min3_f32 %0, %1, %2, %3" : "=v"(d) : "v"(a), "v"(b), "v"(c)); return d;
}

// ---------------- K1: partial argmin over one code chunk, 4 points per thread
template<int CHUNK>
__global__ __launch_bounds__(TPB) void k_dist(const float* __restrict__ x,
                                              const float* __restrict__ E,
                                              float2* __restrict__ dk) {
#pragma clang fp contract(off)
    __shared__ __align__(16) float lds[5 * CHUNK];
    float* exL = lds;
    float* eyL = lds + CHUNK;
    float* ezL = lds + 2 * CHUNK;
    float* ewL = lds + 3 * CHUNK;
    float* bL  = lds + 4 * CHUNK;

    const int chunk = blockIdx.x;
    const int pblk  = blockIdx.y;
    const int tid   = threadIdx.x;
    const int kbase = chunk * CHUNK;

    // Stage SoA + fused bnorm (squares individually rounded, sequential adds)
    for (int i = tid; i < CHUNK; i += TPB) {
        float4 e = ((const float4*)E)[kbase + i];
        exL[i] = e.x; eyL[i] = e.y; ezL[i] = e.z; ewL[i] = e.w;
        bL[i]  = ((e.x * e.x + e.y * e.y) + e.z * e.z) + e.w * e.w;
    }
    __syncthreads();

    // 4 points per thread, stride TPB for coalesced x loads
    int p_[PPT];
    v2f X0[PPT], X1[PPT], X2[PPT], X3[PPT], Av[PPT];
#pragma unroll
    for (int i = 0; i < PPT; ++i) {
        const int p  = pblk * PTS_PER_BLK + i * TPB + tid;
        p_[i] = p;
        const int t  = p >> 12, s = p & 4095;
        const int xb = t * 16384 + s;
        const float x0 = x[xb];
        const float x1 = x[xb + 4096];
        const float x2 = x[xb + 8192];
        const float x3 = x[xb + 12288];
        const float a  = ((x0 * x0 + x1 * x1) + x2 * x2) + x3 * x3;
        X0[i] = v2f{x0, x0}; X1[i] = v2f{x1, x1};
        X2[i] = v2f{x2, x2}; X3[i] = v2f{x3, x3};
        Av[i] = v2f{a, a};
    }
    const v2f M2 = {-2.0f, -2.0f};

    float bd[PPT]; int bk[PPT];
#pragma unroll
    for (int i = 0; i < PPT; ++i) { bd[i] = FLT_MAX; bk[i] = 0; }

#pragma unroll 2
    for (int q = 0; q < CHUNK / 4; ++q) {      // 4 codes x 4 points per iter
        float4 vx = *(const float4*)(exL + 4 * q);
        float4 vy = *(const float4*)(eyL + 4 * q);
        float4 vz = *(const float4*)(ezL + 4 * q);
        float4 vw = *(const float4*)(ewL + 4 * q);
        float4 vb = *(const float4*)(bL  + 4 * q);

        const v2f ex0 = {vx.x, vx.y}, ex1 = {vx.z, vx.w};
        const v2f ey0 = {vy.x, vy.y}, ey1 = {vy.z, vy.w};
        const v2f ez0 = {vz.x, vz.y}, ez1 = {vz.z, vz.w};
        const v2f ew0 = {vw.x, vw.y}, ew1 = {vw.z, vw.w};
        const v2f b0  = {vb.x, vb.y}, b1  = {vb.z, vb.w};
        const int kq = kbase + 4 * q;

#pragma unroll
        for (int i = 0; i < PPT; ++i) {
            // m = fma(x3,ew, fma(x2,ez, fma(x1,ey, x0*ex)))  (BLAS chain, R1-verified)
            v2f m0 = pk_fma(X3[i], ew0, pk_fma(X2[i], ez0, pk_fma(X1[i], ey0, pk_mul(X0[i], ex0))));
            v2f m1 = pk_fma(X3[i], ew1, pk_fma(X2[i], ez1, pk_fma(X1[i], ey1, pk_mul(X0[i], ex1))));
            // fma(-2,m,(a+b)) == (a+b) - fl(2m) bitwise (2m exact, one rounding each)
            v2f d0 = pk_fma(M2, m0, pk_add(Av[i], b0));
            v2f d1 = pk_fma(M2, m1, pk_add(Av[i], b1));
            // tournament min + first-index equality select == sequential strict-<
            float bd4 = min3f(min3f(bd[i], d0.x, d0.y), d1.x, d1.y);
            int sel = (d1.x == bd4) ? 2 : 3;
            sel = (d0.y == bd4) ? 1 : sel;
            sel = (d0.x == bd4) ? 0 : sel;
            bk[i] = (bd4 != bd[i]) ? (kq + sel) : bk[i];   // tie -> keep earlier
            bd[i] = bd4;
        }
    }
#pragma unroll
    for (int i = 0; i < PPT; ++i)
        dk[chunk * NPTS + p_[i]] = make_float2(bd[i], __int_as_float(bk[i]));
}

// ---------------- K2: merge chunks, gather, z_q_st, per-block loss partial
__global__ __launch_bounds__(256) void k_final(const float* __restrict__ x,
                                               const float* __restrict__ E,
                                               const float2* __restrict__ dk,
                                               float* __restrict__ out,
                                               double* __restrict__ partials,
                                               int nc) {
#pragma clang fp contract(off)
    const int tid = threadIdx.x;
    const int p   = blockIdx.x * 256 + tid;    // 32 blocks x 256 threads
    const int t   = p >> 12;
    const int s   = p & 4095;

    float bd = FLT_MAX;
    int   bk = 0;
#pragma unroll 8
    for (int c = 0; c < nc; ++c) {             // increasing k ranges
        float2 v = dk[c * NPTS + p];
        if (v.x < bd) { bd = v.x; bk = __float_as_int(v.y); }  // strict <
    }

    float4 e = ((const float4*)E)[bk];
    float ev[4] = {e.x, e.y, e.z, e.w};
    double ls = 0.0;
    const int xb = t * 16384 + s;
#pragma unroll
    for (int ch = 0; ch < 4; ++ch) {
        int idx = xb + ch * 4096;
        float xv   = x[idx];
        float diff = ev[ch] - xv;              // fl(z_q - x)
        float sq   = diff * diff;              // fl(diff^2)
        out[idx]   = xv + diff;                // z_q_st = fl(x + fl(z_q - x))
        ls += (double)sq;
    }
    out[32769 + p] = (float)bk;                // codes as float

    __shared__ double sred[256];
    sred[tid] = ls;
    __syncthreads();
    for (int o = 128; o > 0; o >>= 1) {
        if (tid < o) sred[tid] += sred[tid + o];
        __syncthreads();
    }
    if (tid == 0) partials[blockIdx.x] = sred[0];
}

// ---------------- K3: finalize qloss
__global__ void k_loss(const double* __restrict__ partials,
                       float* __restrict__ out) {
#pragma clang fp contract(off)
    if (threadIdx.x == 0 && blockIdx.x == 0) {
        double sum = 0.0;
        for (int i = 0; i < 32; ++i) sum += partials[i];
        float mu = (float)(sum * (1.0 / 32768.0));   // /32768 exact
        float q  = mu + 0.1f * mu;                   // mean1 + BETA*mean2
        out[32768] = q;
    }
}

extern "C" void kernel_launch(void* const* d_in, const int* in_sizes, int n_in,
                              void* d_out, int out_size, void* d_ws, size_t ws_size,
                              hipStream_t stream) {
    const float* x = (const float*)d_in[0];   // (1,2,4,64,64)
    const float* E = (const float*)d_in[1];   // (32768,4)
    float* out = (float*)d_out;               // 40961 floats

    char* ws = (char*)d_ws;
    double* partials = (double*)ws;                    // 1 KB
    float2* dk       = (float2*)(ws + 1024);

    // dk needs nc*8192*8B: NC=128 -> 8.4MB, NC=64 -> 4.2MB (proven in R4), NC=32 -> 2.1MB
    const size_t need128 = 1024 + (size_t)128 * NPTS * 8;
    const size_t need64  = 1024 + (size_t)64  * NPTS * 8;
    if (ws_size >= need128) {
        dim3 g(128, NPB);
        k_dist<256><<<g, TPB, 0, stream>>>(x, E, dk);
        k_final<<<NPTS / 256, 256, 0, stream>>>(x, E, dk, out, partials, 128);
    } else if (ws_size >= need64) {
        dim3 g(64, NPB);
        k_dist<512><<<g, TPB, 0, stream>>>(x, E, dk);
        k_final<<<NPTS / 256, 256, 0, stream>>>(x, E, dk, out, partials, 64);
    } else {
        dim3 g(32, NPB);
        k_dist<1024><<<g, TPB, 0, stream>>>(x, E, dk);
        k_final<<<NPTS / 256, 256, 0, stream>>>(x, E, dk, out, partials, 32);
    }
    k_loss<<<1, 64, 0, stream>>>(partials, out);
}

// Round 10
// 72.520 us; speedup vs baseline: 1.3156x; 1.3156x over previous
//
#include <hip/hip_runtime.h>
#include <cfloat>

#define KC   32768
#define NPTS 8192
#define TPB  256
#define PPT  4
#define PTS_PER_BLK (TPB * PPT)        // 1024
#define NPB  (NPTS / PTS_PER_BLK)      // 8

typedef float v2f __attribute__((ext_vector_type(2)));

// Packed fp32 (IEEE per 32-bit half) — bit-identical to scalar chain (verified R1-R4)
__device__ __forceinline__ v2f pk_mul(v2f a, v2f b) {
    v2f d; asm("v_pk_mul_f32 %0, %1, %2" : "=v"(d) : "v"(a), "v"(b)); return d;
}
__device__ __forceinline__ v2f pk_fma(v2f a, v2f b, v2f c) {
    v2f d; asm("v_pk_fma_f32 %0, %1, %2, %3" : "=v"(d) : "v"(a), "v"(b), "v"(c)); return d;
}
__device__ __forceinline__ v2f pk_add(v2f a, v2f b) {
    v2f d; asm("v_pk_add_f32 %0, %1, %2" : "=v"(d) : "v"(a), "v"(b)); return d;
}
__device__ __forceinline__ float min3f(float a, float b, float c) {
    float d; asm("v_min3_f32 %0, %1, %2, %3" : "=v"(d) : "v"(a), "v"(b), "v"(c)); return d;
}

// ---------------- K1: partial argmin over one code chunk, 4 points per thread
template<int CHUNK>
__global__ __launch_bounds__(TPB) void k_dist(const float* __restrict__ x,
                                              const float* __restrict__ E,
                                              float2* __restrict__ dk) {
#pragma clang fp contract(off)
    __shared__ __align__(16) float lds[5 * CHUNK];
    float* exL = lds;
    float* eyL = lds + CHUNK;
    float* ezL = lds + 2 * CHUNK;
    float* ewL = lds + 3 * CHUNK;
    float* bL  = lds + 4 * CHUNK;

    const int chunk = blockIdx.x;
    const int pblk  = blockIdx.y;
    const int tid   = threadIdx.x;
    const int kbase = chunk * CHUNK;

    // Stage SoA + fused bnorm (squares individually rounded, sequential adds)
    for (int i = tid; i < CHUNK; i += TPB) {
        float4 e = ((const float4*)E)[kbase + i];
        exL[i] = e.x; eyL[i] = e.y; ezL[i] = e.z; ewL[i] = e.w;
        bL[i]  = ((e.x * e.x + e.y * e.y) + e.z * e.z) + e.w * e.w;
    }
    __syncthreads();

    // 4 points per thread, stride TPB for coalesced x loads
    int p_[PPT];
    v2f X0[PPT], X1[PPT], X2[PPT], X3[PPT], Av[PPT];
#pragma unroll
    for (int i = 0; i < PPT; ++i) {
        const int p  = pblk * PTS_PER_BLK + i * TPB + tid;
        p_[i] = p;
        const int t  = p >> 12, s = p & 4095;
        const int xb = t * 16384 + s;
        const float x0 = x[xb];
        const float x1 = x[xb + 4096];
        const float x2 = x[xb + 8192];
        const float x3 = x[xb + 12288];
        const float a  = ((x0 * x0 + x1 * x1) + x2 * x2) + x3 * x3;
        X0[i] = v2f{x0, x0}; X1[i] = v2f{x1, x1};
        X2[i] = v2f{x2, x2}; X3[i] = v2f{x3, x3};
        Av[i] = v2f{a, a};
    }
    const v2f M2 = {-2.0f, -2.0f};

    float bd[PPT]; int bk[PPT];
#pragma unroll
    for (int i = 0; i < PPT; ++i) { bd[i] = FLT_MAX; bk[i] = 0; }

#pragma unroll 2
    for (int q = 0; q < CHUNK / 4; ++q) {      // 4 codes x 4 points per iter
        float4 vx = *(const float4*)(exL + 4 * q);
        float4 vy = *(const float4*)(eyL + 4 * q);
        float4 vz = *(const float4*)(ezL + 4 * q);
        float4 vw = *(const float4*)(ewL + 4 * q);
        float4 vb = *(const float4*)(bL  + 4 * q);

        const v2f ex0 = {vx.x, vx.y}, ex1 = {vx.z, vx.w};
        const v2f ey0 = {vy.x, vy.y}, ey1 = {vy.z, vy.w};
        const v2f ez0 = {vz.x, vz.y}, ez1 = {vz.z, vz.w};
        const v2f ew0 = {vw.x, vw.y}, ew1 = {vw.z, vw.w};
        const v2f b0  = {vb.x, vb.y}, b1  = {vb.z, vb.w};
        const int kq = kbase + 4 * q;

#pragma unroll
        for (int i = 0; i < PPT; ++i) {
            // m = fma(x3,ew, fma(x2,ez, fma(x1,ey, x0*ex)))  (BLAS chain, R1-verified)
            v2f m0 = pk_fma(X3[i], ew0, pk_fma(X2[i], ez0, pk_fma(X1[i], ey0, pk_mul(X0[i], ex0))));
            v2f m1 = pk_fma(X3[i], ew1, pk_fma(X2[i], ez1, pk_fma(X1[i], ey1, pk_mul(X0[i], ex1))));
            // fma(-2,m,(a+b)) == (a+b) - fl(2m) bitwise (2m exact, one rounding each)
            v2f d0 = pk_fma(M2, m0, pk_add(Av[i], b0));
            v2f d1 = pk_fma(M2, m1, pk_add(Av[i], b1));
            // tournament min + first-index equality select == sequential strict-<
            float bd4 = min3f(min3f(bd[i], d0.x, d0.y), d1.x, d1.y);
            int sel = (d1.x == bd4) ? 2 : 3;
            sel = (d0.y == bd4) ? 1 : sel;
            sel = (d0.x == bd4) ? 0 : sel;
            bk[i] = (bd4 != bd[i]) ? (kq + sel) : bk[i];   // tie -> keep earlier
            bd[i] = bd4;
        }
    }
#pragma unroll
    for (int i = 0; i < PPT; ++i)
        dk[chunk * NPTS + p_[i]] = make_float2(bd[i], __int_as_float(bk[i]));
}

// ---------------- K2: parallel lexicographic merge + gather + z_q_st + loss
// 8 sub-lanes per point. Lexicographic (d, tie->smaller k) merge is
// order-independent and equals the reference's first-index argmin, because
// each partial's k is already the smallest-k achiever of its chunk range.
template<int NC>
__global__ __launch_bounds__(256) void k_merge(const float* __restrict__ x,
                                               const float* __restrict__ E,
                                               const float2* __restrict__ dk,
                                               float* __restrict__ out,
                                               double* __restrict__ partials) {
#pragma clang fp contract(off)
    const int tid  = threadIdx.x;
    const int sub  = tid & 7;
    const int pidx = tid >> 3;                 // 0..31
    const int p    = blockIdx.x * 32 + pidx;   // 256 blocks x 32 points
    const int t    = p >> 12, s = p & 4095;

    float bd = FLT_MAX;
    int   bk = 0;
#pragma unroll
    for (int i = 0; i < NC / 8; ++i) {         // this thread's chunks increase
        float2 v = dk[(sub + 8 * i) * NPTS + p];
        if (v.x < bd) { bd = v.x; bk = __float_as_int(v.y); }  // strict <
    }
    // butterfly across the 8 sub-lanes (adjacent lanes, same wave)
#pragma unroll
    for (int m = 1; m <= 4; m <<= 1) {
        float d2 = __shfl_xor(bd, m);
        int   k2 = __shfl_xor(bk, m);
        if (d2 < bd || (d2 == bd && k2 < bk)) { bd = d2; bk = k2; }
    }

    double ls = 0.0;
    if (sub < 4) {                             // one channel per sub-lane
        const int ch  = sub;
        const int idx = t * 16384 + s + ch * 4096;
        float xv   = x[idx];
        float ev   = E[bk * 4 + ch];
        float diff = ev - xv;                  // fl(z_q - x)
        float sq   = diff * diff;              // fl(diff^2)
        out[idx]   = xv + diff;                // z_q_st = fl(x + fl(z_q - x))
        ls = (double)sq;
        if (ch == 0) out[32769 + p] = (float)bk;  // codes as float
    }
    // wave sum (subs 4-7 contribute 0), then 4 waves via LDS
#pragma unroll
    for (int m = 1; m < 64; m <<= 1) ls += __shfl_xor(ls, m);
    __shared__ double sred[4];
    if ((tid & 63) == 0) sred[tid >> 6] = ls;
    __syncthreads();
    if (tid == 0) partials[blockIdx.x] = sred[0] + sred[1] + sred[2] + sred[3];
}

// ---------------- K3: finalize qloss (double accum is exact enough that any
// summation order rounds to the same fp32 — verified absmax 0.0 through R9)
__global__ void k_loss(const double* __restrict__ partials,
                       float* __restrict__ out) {
#pragma clang fp contract(off)
    if (threadIdx.x == 0 && blockIdx.x == 0) {
        double sum = 0.0;
        for (int i = 0; i < 256; ++i) sum += partials[i];
        float mu = (float)(sum * (1.0 / 32768.0));   // /32768 exact
        float q  = mu + 0.1f * mu;                   // mean1 + BETA*mean2
        out[32768] = q;
    }
}

extern "C" void kernel_launch(void* const* d_in, const int* in_sizes, int n_in,
                              void* d_out, int out_size, void* d_ws, size_t ws_size,
                              hipStream_t stream) {
    const float* x = (const float*)d_in[0];   // (1,2,4,64,64)
    const float* E = (const float*)d_in[1];   // (32768,4)
    float* out = (float*)d_out;               // 40961 floats

    char* ws = (char*)d_ws;
    double* partials = (double*)ws;                    // 2 KB
    float2* dk       = (float2*)(ws + 2048);

    // dk bytes = NC*8192*8: NC=256 -> 16.8MB (try), NC=128 -> 8.4MB (proven R9)
    const size_t need256 = 2048 + (size_t)256 * NPTS * 8;
    if (ws_size >= need256) {
        dim3 g(256, NPB);
        k_dist<128><<<g, TPB, 0, stream>>>(x, E, dk);
        k_merge<256><<<256, 256, 0, stream>>>(x, E, dk, out, partials);
    } else {
        dim3 g(128, NPB);
        k_dist<256><<<g, TPB, 0, stream>>>(x, E, dk);
        k_merge<128><<<256, 256, 0, stream>>>(x, E, dk, out, partials);
    }
    k_loss<<<1, 64, 0, stream>>>(partials, out);
}

// Round 12
// 50.305 us; speedup vs baseline: 1.8965x; 1.4416x over previous
//
#include <hip/hip_runtime.h>
#include <cfloat>

#define KC    32768
#define NPTS  8192
#define TPB   256
#define PPT   8
#define PTS_PER_BLK (TPB * PPT)        // 2048
#define NPB   (NPTS / PTS_PER_BLK)     // 4
#define NC    256
#define CHUNK (KC / NC)                // 128

typedef float v2f __attribute__((ext_vector_type(2)));

// Packed fp32 (IEEE per 32-bit half) — bit-identical to scalar chain (verified R1-R10)
__device__ __forceinline__ v2f pk_fma(v2f a, v2f b, v2f c) {
    v2f d; asm("v_pk_fma_f32 %0, %1, %2, %3" : "=v"(d) : "v"(a), "v"(b), "v"(c)); return d;
}
__device__ __forceinline__ v2f pk_add(v2f a, v2f b) {
    v2f d; asm("v_pk_add_f32 %0, %1, %2" : "=v"(d) : "v"(a), "v"(b)); return d;
}
// Broadcast half H of the PAIR src0 to both result halves (VOP3P op_sel).
// All operands are 64-bit pairs — fixes R11's single-VGPR operand error.
template<int H>
__device__ __forceinline__ v2f pk_mul_s(v2f a, v2f b) {
    v2f d;
    if constexpr (H == 0)
        asm("v_pk_mul_f32 %0, %1, %2 op_sel:[0,0] op_sel_hi:[0,1]" : "=v"(d) : "v"(a), "v"(b));
    else
        asm("v_pk_mul_f32 %0, %1, %2 op_sel:[1,0] op_sel_hi:[1,1]" : "=v"(d) : "v"(a), "v"(b));
    return d;
}
template<int H>
__device__ __forceinline__ v2f pk_fma_s(v2f a, v2f b, v2f c) {
    v2f d;
    if constexpr (H == 0)
        asm("v_pk_fma_f32 %0, %1, %2, %3 op_sel:[0,0,0] op_sel_hi:[0,1,1]" : "=v"(d) : "v"(a), "v"(b), "v"(c));
    else
        asm("v_pk_fma_f32 %0, %1, %2, %3 op_sel:[1,0,0] op_sel_hi:[1,1,1]" : "=v"(d) : "v"(a), "v"(b), "v"(c));
    return d;
}
__device__ __forceinline__ float min3f(float a, float b, float c) {
    float d; asm("v_min3_f32 %0, %1, %2, %3" : "=v"(d) : "v"(a), "v"(b), "v"(c)); return d;
}

// ---------------- K1: per-chunk MIN-DISTANCE ONLY (no index), 8 points/thread
__global__ __launch_bounds__(TPB) void k_dist(const float* __restrict__ x,
                                              const float* __restrict__ E,
                                              float* __restrict__ dmn) {
#pragma clang fp contract(off)
    __shared__ __align__(16) float lds[5 * CHUNK];
    float* exL = lds;
    float* eyL = lds + CHUNK;
    float* ezL = lds + 2 * CHUNK;
    float* ewL = lds + 3 * CHUNK;
    float* bL  = lds + 4 * CHUNK;

    const int chunk = blockIdx.x;
    const int pblk  = blockIdx.y;
    const int tid   = threadIdx.x;
    const int kbase = chunk * CHUNK;

    // Stage SoA + fused bnorm (squares individually rounded, sequential adds)
    for (int i = tid; i < CHUNK; i += TPB) {
        float4 e = ((const float4*)E)[kbase + i];
        exL[i] = e.x; eyL[i] = e.y; ezL[i] = e.z; ewL[i] = e.w;
        bL[i]  = ((e.x * e.x + e.y * e.y) + e.z * e.z) + e.w * e.w;
    }
    __syncthreads();

    // 8 points/thread: packed pairs X01={x0,x1}, X23={x2,x3}, Av={a,a}
    v2f X01[PPT], X23[PPT], Av[PPT];
#pragma unroll
    for (int i = 0; i < PPT; ++i) {
        const int p  = pblk * PTS_PER_BLK + i * TPB + tid;
        const int t  = p >> 12, s = p & 4095;
        const int xb = t * 16384 + s;
        const float x0 = x[xb];
        const float x1 = x[xb + 4096];
        const float x2 = x[xb + 8192];
        const float x3 = x[xb + 12288];
        X01[i] = v2f{x0, x1};
        X23[i] = v2f{x2, x3};
        const float a = ((x0 * x0 + x1 * x1) + x2 * x2) + x3 * x3;
        Av[i] = v2f{a, a};
    }
    const v2f M2 = {-2.0f, -2.0f};

    float bd[PPT];
#pragma unroll
    for (int i = 0; i < PPT; ++i) bd[i] = FLT_MAX;

#pragma unroll 2
    for (int q = 0; q < CHUNK / 4; ++q) {      // 4 codes x 8 points per iter
        float4 vx = *(const float4*)(exL + 4 * q);
        float4 vy = *(const float4*)(eyL + 4 * q);
        float4 vz = *(const float4*)(ezL + 4 * q);
        float4 vw = *(const float4*)(ewL + 4 * q);
        float4 vb = *(const float4*)(bL  + 4 * q);

        const v2f ex0 = {vx.x, vx.y}, ex1 = {vx.z, vx.w};
        const v2f ey0 = {vy.x, vy.y}, ey1 = {vy.z, vy.w};
        const v2f ez0 = {vz.x, vz.y}, ez1 = {vz.z, vz.w};
        const v2f ew0 = {vw.x, vw.y}, ew1 = {vw.z, vw.w};
        const v2f b0  = {vb.x, vb.y}, b1  = {vb.z, vb.w};

#pragma unroll
        for (int i = 0; i < PPT; ++i) {
            // m = fma(x3,ew, fma(x2,ez, fma(x1,ey, x0*ex)))  (BLAS chain, R1-verified)
            v2f m0 = pk_fma_s<1>(X23[i], ew0, pk_fma_s<0>(X23[i], ez0,
                      pk_fma_s<1>(X01[i], ey0, pk_mul_s<0>(X01[i], ex0))));
            v2f m1 = pk_fma_s<1>(X23[i], ew1, pk_fma_s<0>(X23[i], ez1,
                      pk_fma_s<1>(X01[i], ey1, pk_mul_s<0>(X01[i], ex1))));
            // d = fma(-2,m,(a+b)) == (a+b) - fl(2m) bitwise
            v2f d0 = pk_fma(M2, m0, pk_add(Av[i], b0));
            v2f d1 = pk_fma(M2, m1, pk_add(Av[i], b1));
            bd[i] = min3f(min3f(bd[i], d0.x, d0.y), d1.x, d1.y);  // min only
        }
    }
#pragma unroll
    for (int i = 0; i < PPT; ++i) {
        const int p = pblk * PTS_PER_BLK + i * TPB + tid;
        dmn[chunk * NPTS + p] = bd[i];
    }
}

// ---------------- K2: merge chunk-mins, recover first-index k, gather, loss
// dmin = min over chunk-mins (exact, order-independent). First chunk whose
// min == dmin contains the reference's first-index argmin; rescan its 128
// codes with the bitwise-identical scalar chain to find the first k.
__global__ __launch_bounds__(256) void k_merge(const float* __restrict__ x,
                                               const float* __restrict__ E,
                                               const float* __restrict__ dmn,
                                               float* __restrict__ out,
                                               double* __restrict__ partials) {
#pragma clang fp contract(off)
    const int tid  = threadIdx.x;
    const int sub  = tid & 7;
    const int pidx = tid >> 3;                 // 0..31
    const int p    = blockIdx.x * 32 + pidx;   // 256 blocks x 32 points
    const int t    = p >> 12, s = p & 4095;
    const int xb   = t * 16384 + s;

    const float x0 = x[xb];
    const float x1 = x[xb + 4096];
    const float x2 = x[xb + 8192];
    const float x3 = x[xb + 12288];
    const float a  = ((x0 * x0 + x1 * x1) + x2 * x2) + x3 * x3;

    // min over chunks with first-chunk tie -> (d, c) lexicographic
    float bd = FLT_MAX;
    int   bc = 0x7fffffff;
#pragma unroll
    for (int i = 0; i < NC / 8; ++i) {
        const int c = sub + 8 * i;             // ascending per sub
        float d = dmn[c * NPTS + p];
        if (d < bd) { bd = d; bc = c; }        // strict <: earliest c in sub set
    }
#pragma unroll
    for (int m = 1; m <= 4; m <<= 1) {
        float d2 = __shfl_xor(bd, m);
        int   c2 = __shfl_xor(bc, m);
        if (d2 < bd || (d2 == bd && c2 < bc)) { bd = d2; bc = c2; }
    }

    // rescan chunk bc (128 codes): sub handles j = sub*16 .. sub*16+15
    const int kb = bc * CHUNK;
    int jloc = 1 << 30;
    for (int jj = 0; jj < 16; ++jj) {
        const int j = sub * 16 + jj;
        float4 e = ((const float4*)E)[kb + j];
        float bn = ((e.x * e.x + e.y * e.y) + e.z * e.z) + e.w * e.w;
        float m_ = __builtin_fmaf(x3, e.w, __builtin_fmaf(x2, e.z,
                    __builtin_fmaf(x1, e.y, x0 * e.x)));
        float t_ = a + bn;
        float d_ = __builtin_fmaf(-2.0f, m_, t_);
        if (d_ == bd) jloc = min(jloc, j);     // ascending j -> first match
    }
#pragma unroll
    for (int m = 1; m <= 4; m <<= 1) jloc = min(jloc, __shfl_xor(jloc, m));
    const int bk = kb + (jloc & (CHUNK - 1));  // clamp guards OOB if mismatch

    double ls = 0.0;
    if (sub < 4) {                             // one channel per sub-lane
        const int ch  = sub;
        const int idx = xb + ch * 4096;
        float xv   = x[idx];
        float ev   = E[bk * 4 + ch];
        float diff = ev - xv;                  // fl(z_q - x)
        float sq   = diff * diff;              // fl(diff^2)
        out[idx]   = xv + diff;                // z_q_st = fl(x + fl(z_q - x))
        ls = (double)sq;
        if (ch == 0) out[32769 + p] = (float)bk;  // codes as float
    }
#pragma unroll
    for (int m = 1; m < 64; m <<= 1) ls += __shfl_xor(ls, m);
    __shared__ double sred[4];
    if ((tid & 63) == 0) sred[tid >> 6] = ls;
    __syncthreads();
    if (tid == 0) partials[blockIdx.x] = sred[0] + sred[1] + sred[2] + sred[3];
}

// ---------------- K3: finalize qloss
__global__ void k_loss(const double* __restrict__ partials,
                       float* __restrict__ out) {
#pragma clang fp contract(off)
    if (threadIdx.x == 0 && blockIdx.x == 0) {
        double sum = 0.0;
        for (int i = 0; i < 256; ++i) sum += partials[i];
        float mu = (float)(sum * (1.0 / 32768.0));   // /32768 exact
        float q  = mu + 0.1f * mu;                   // mean1 + BETA*mean2
        out[32768] = q;
    }
}

extern "C" void kernel_launch(void* const* d_in, const int* in_sizes, int n_in,
                              void* d_out, int out_size, void* d_ws, size_t ws_size,
                              hipStream_t stream) {
    const float* x = (const float*)d_in[0];   // (1,2,4,64,64)
    const float* E = (const float*)d_in[1];   // (32768,4)
    float* out = (float*)d_out;               // 40961 floats

    char* ws = (char*)d_ws;
    double* partials = (double*)ws;                    // 2 KB
    float*  dmn      = (float*)(ws + 2048);            // 256*8192*4 = 8.4 MB (ws >=16.8MB proven R10)

    dim3 g(NC, NPB);
    k_dist<<<g, TPB, 0, stream>>>(x, E, dmn);
    k_merge<<<NPTS / 32, 256, 0, stream>>>(x, E, dmn, out, partials);
    k_loss<<<1, 64, 0, stream>>>(partials, out);
}